// Round 4
// baseline (575.834 us; speedup 1.0000x reference)
//
#include <hip/hip_runtime.h>
#include <math.h>

#define B_ 256
#define A_ 196
#define R_ 1024
#define V_ 10000
#define G4 4096
#define M_ (B_ * A_)   // 50176

typedef __bf16 bf16x8 __attribute__((ext_vector_type(8)));
typedef float f32x4 __attribute__((ext_vector_type(4)));

// ws layout in floats (~21.8 MB)
#define OFF_ATTH   0
#define OFF_SCORE  50176
#define OFF_WEIGHT 100352
#define OFF_ATTRES 150528
#define OFF_P0     412672
#define OFF_P1     1461248
#define OFF_NHBF   2509824
#define OFF_LOGITS 2640896
#define OFF_PACKA  5200896   // a2a_w bf16 [208][1024]
#define OFF_PACKH  5307392   // h2a_w bf16 [256][1024]

__device__ __forceinline__ float tanh_fast(float x) {
    float e = __expf(2.f * x);
    return 1.f - 2.f / (e + 1.f);
}
__device__ __forceinline__ float sigmoid_fast(float x) {
    return 1.f / (1.f + __expf(-x));
}

__device__ __forceinline__ bf16x8 cvt8(float4 f0, float4 f1) {
    bf16x8 v;
    v[0] = (__bf16)f0.x; v[1] = (__bf16)f0.y; v[2] = (__bf16)f0.z; v[3] = (__bf16)f0.w;
    v[4] = (__bf16)f1.x; v[5] = (__bf16)f1.y; v[6] = (__bf16)f1.z; v[7] = (__bf16)f1.w;
    return v;
}

// ---------------- kernel 0: pack a2a_w and h2a_w to bf16 (zero-padded rows) ---
__global__ void pack_kernel(const float* __restrict__ a2a_w,
                            const float* __restrict__ h2a_w,
                            __bf16* __restrict__ packA,   // [208][1024]
                            __bf16* __restrict__ packH) { // [256][1024]
    int row = blockIdx.x;
    int c = threadIdx.x * 4;
    if (row < 208) {
        float4 f = (row < A_) ? *(const float4*)(a2a_w + (size_t)row * R_ + c)
                              : make_float4(0.f, 0.f, 0.f, 0.f);
        __bf16* p = packA + (size_t)row * R_ + c;
        p[0] = (__bf16)f.x; p[1] = (__bf16)f.y; p[2] = (__bf16)f.z; p[3] = (__bf16)f.w;
    } else {
        int r2 = row - 208;
        float4 f = (r2 < A_) ? *(const float4*)(h2a_w + (size_t)r2 * R_ + c)
                             : make_float4(0.f, 0.f, 0.f, 0.f);
        __bf16* p = packH + (size_t)r2 * R_ + c;
        p[0] = (__bf16)f.x; p[1] = (__bf16)f.y; p[2] = (__bf16)f.z; p[3] = (__bf16)f.w;
    }
}

// ---------------- kernel 1: att_h = prev_h @ h2a_w.T + h2a_b  (MFMA) ----------
__global__ __launch_bounds__(256)
void att_h_gemm(const float* __restrict__ prev_h,
                const __bf16* __restrict__ packH,
                const float* __restrict__ h2a_b,
                float* __restrict__ att_h) {
    __shared__ alignas(16) __bf16 As[64][40];
    __shared__ alignas(16) __bf16 Bs[64][40];
    int tid = threadIdx.x;
    int m0 = blockIdx.x * 64, n0 = blockIdx.y * 64;
    int lane = tid & 63, w = tid >> 6, ln = lane & 15, quad = lane >> 4;
    int arow = tid >> 2, akq = (tid & 3) * 8;

    f32x4 acc[4];
#pragma unroll
    for (int t = 0; t < 4; ++t) acc[t] = {0.f, 0.f, 0.f, 0.f};

    const float* Asrc = prev_h + (size_t)(m0 + arow) * R_ + akq;
    const __bf16* Bsrc = packH + (size_t)(n0 + arow) * R_ + akq;

    float4 pa0 = *(const float4*)Asrc;
    float4 pa1 = *(const float4*)(Asrc + 4);
    bf16x8 pb = *(const bf16x8*)Bsrc;

    for (int k0 = 0; k0 < R_; k0 += 32) {
        __syncthreads();
        *(bf16x8*)&As[arow][akq] = cvt8(pa0, pa1);
        *(bf16x8*)&Bs[arow][akq] = pb;
        __syncthreads();
        if (k0 + 32 < R_) {
            pa0 = *(const float4*)(Asrc + k0 + 32);
            pa1 = *(const float4*)(Asrc + k0 + 36);
            pb = *(const bf16x8*)(Bsrc + k0 + 32);
        }
        bf16x8 a = *(bf16x8*)&As[w * 16 + ln][quad * 8];
#pragma unroll
        for (int t = 0; t < 4; ++t) {
            bf16x8 b = *(bf16x8*)&Bs[t * 16 + ln][quad * 8];
            acc[t] = __builtin_amdgcn_mfma_f32_16x16x32_bf16(a, b, acc[t], 0, 0, 0);
        }
    }
#pragma unroll
    for (int t = 0; t < 4; ++t) {
#pragma unroll
        for (int r = 0; r < 4; ++r) {
            int m = m0 + w * 16 + quad * 4 + r;
            int n = n0 + t * 16 + ln;
            if (n < A_) att_h[m * A_ + n] = acc[t][r] + h2a_b[n];
        }
    }
}

// ---------------- kernel 2: FUSED score GEMM + softmax + att_res ---------------
// One block per batch (256 blocks = 1/CU), 512 threads = 8 independent waves.
// GEMM phase: wave w owns rows w*32..w*32+31 (slots >=196 clamped/discarded).
// B (packA, 416 KB total) read DIRECTLY to registers from L2 -- no LDS, no
// barriers: waves are self-paced, TLP+depth-2 A-ring hides latency.
// Per phase issue order: B(p) first 7 frags, A(p+1) prefetch, last 6 B frags,
// then MFMAs -- so compiler waitcnts on B leave the A prefetch in flight,
// and at most ~7 B frags are register-live at once.
// Then in-block softmax over the 196 scores, then att_res pass re-reading
// att[b] (784 KB) while it is still L2/L3-hot.
__global__ __launch_bounds__(512, 1)
void att_fused(const float* __restrict__ att,
               const __bf16* __restrict__ packA,  // [208][1024] bf16, zero-padded
               const float* __restrict__ a2a_b,
               const float* __restrict__ d2d_w,
               const float* __restrict__ d2d_b,
               const float* __restrict__ att_h,   // [B][196]
               float* __restrict__ att_res) {
    __shared__ float sm[256];    // scores then weights
    __shared__ float red[512];
    const int b = blockIdx.x;
    const int tid = threadIdx.x;
    const int w = tid >> 6, lane = tid & 63, ln = lane & 15, quad = lane >> 4;

    // A row slots for this wave's two 16-row fragments
    int r0 = w * 32 + ln;        int r0c = r0 < A_ ? r0 : A_ - 1;
    int r1 = w * 32 + 16 + ln;   int r1c = r1 < A_ ? r1 : A_ - 1;
    const float* Ap0 = att + (size_t)(b * A_ + r0c) * R_ + quad * 8;
    const float* Ap1 = att + (size_t)(b * A_ + r1c) * R_ + quad * 8;
    const __bf16* Bb = packA + (size_t)ln * R_ + quad * 8;

    f32x4 acc0[13], acc1[13];
#pragma unroll
    for (int t = 0; t < 13; ++t) {
        acc0[t] = {0.f, 0.f, 0.f, 0.f};
        acc1[t] = {0.f, 0.f, 0.f, 0.f};
    }

    // A phase-0 in flight
    float4 a00 = *(const float4*)Ap0, a01 = *(const float4*)(Ap0 + 4);
    float4 a10 = *(const float4*)Ap1, a11 = *(const float4*)(Ap1 + 4);

    for (int p = 0; p < 32; ++p) {
        // B(p) first chunk: 7 fragments direct from L2 (oldest in FIFO)
        bf16x8 bt0[7];
#pragma unroll
        for (int t = 0; t < 7; ++t)
            bt0[t] = *(const bf16x8*)(Bb + (size_t)t * 16 * R_ + p * 32);
        // A(p+1) prefetch (issued before any B-consuming MFMA forces a wait)
        int pn = p + 1 < 32 ? p + 1 : 31;
        float4 n00 = *(const float4*)(Ap0 + pn * 32);
        float4 n01 = *(const float4*)(Ap0 + pn * 32 + 4);
        float4 n10 = *(const float4*)(Ap1 + pn * 32);
        float4 n11 = *(const float4*)(Ap1 + pn * 32 + 4);
        // B(p) second chunk: 6 fragments
        bf16x8 bt1[6];
#pragma unroll
        for (int t = 0; t < 6; ++t)
            bt1[t] = *(const bf16x8*)(Bb + (size_t)(t + 7) * 16 * R_ + p * 32);
        bf16x8 af0 = cvt8(a00, a01);
        bf16x8 af1 = cvt8(a10, a11);
#pragma unroll
        for (int t = 0; t < 7; ++t) {
            acc0[t] = __builtin_amdgcn_mfma_f32_16x16x32_bf16(af0, bt0[t], acc0[t], 0, 0, 0);
            acc1[t] = __builtin_amdgcn_mfma_f32_16x16x32_bf16(af1, bt0[t], acc1[t], 0, 0, 0);
        }
#pragma unroll
        for (int t = 0; t < 6; ++t) {
            acc0[t + 7] = __builtin_amdgcn_mfma_f32_16x16x32_bf16(af0, bt1[t], acc0[t + 7], 0, 0, 0);
            acc1[t + 7] = __builtin_amdgcn_mfma_f32_16x16x32_bf16(af1, bt1[t], acc1[t + 7], 0, 0, 0);
        }
        a00 = n00; a01 = n01; a10 = n10; a11 = n11;
    }

    // ---- epilogue: tanh + d2d dot, wave-local shuffle reduce over ln ----
    float wv[13], bb2[13];
#pragma unroll
    for (int t = 0; t < 13; ++t) {
        int n = t * 16 + ln;
        wv[t] = (n < A_) ? d2d_w[n] : 0.f;
        bb2[t] = (n < A_) ? a2a_b[n] : 0.f;
    }
#pragma unroll
    for (int mf = 0; mf < 2; ++mf) {
#pragma unroll
        for (int r = 0; r < 4; ++r) {
            int slot = w * 32 + mf * 16 + quad * 4 + r;
            float ah = (slot < A_) ? att_h[b * A_ + slot] : 0.f;
            float pv = 0.f;
#pragma unroll
            for (int t = 0; t < 13; ++t) {
                float v = (mf == 0) ? acc0[t][r] : acc1[t][r];
                pv += tanh_fast(v + bb2[t] + ah) * wv[t];
            }
            pv += __shfl_xor(pv, 1);
            pv += __shfl_xor(pv, 2);
            pv += __shfl_xor(pv, 4);
            pv += __shfl_xor(pv, 8);
            if (ln == 0 && slot < A_) sm[slot] = pv;
        }
    }
    __syncthreads();

    // ---- softmax over 196 scores (512-thread tree) ----
    float sval = 0.f, s = -1e30f;
    if (tid < A_) { sval = sm[tid] + d2d_b[0]; s = sval; }
    red[tid] = s; __syncthreads();
    for (int off = 256; off > 0; off >>= 1) {
        if (tid < off) red[tid] = fmaxf(red[tid], red[tid + off]);
        __syncthreads();
    }
    float mx = red[0]; __syncthreads();
    float e = (tid < A_) ? __expf(sval - mx) : 0.f;
    red[tid] = e; __syncthreads();
    for (int off = 256; off > 0; off >>= 1) {
        if (tid < off) red[tid] += red[tid + off];
        __syncthreads();
    }
    float inv = 1.f / red[0];
    if (tid < A_) sm[tid] = e * inv;
    __syncthreads();

    // ---- att_res: thread owns 2 consecutive r columns; att[b] is L2/L3-hot ----
    int rr = tid * 2;
    const float* ap = att + (size_t)b * A_ * R_ + rr;
    float acx = 0.f, acy = 0.f;
    for (int i = 0; i < A_; i += 4) {
        float2 v0 = *(const float2*)(ap + (size_t)(i + 0) * R_);
        float2 v1 = *(const float2*)(ap + (size_t)(i + 1) * R_);
        float2 v2 = *(const float2*)(ap + (size_t)(i + 2) * R_);
        float2 v3 = *(const float2*)(ap + (size_t)(i + 3) * R_);
        float w0 = sm[i], w1 = sm[i + 1], w2 = sm[i + 2], w3 = sm[i + 3];
        acx += v0.x * w0 + v1.x * w1 + v2.x * w2 + v3.x * w3;
        acy += v0.y * w0 + v1.y * w1 + v2.y * w2 + v3.y * w3;
    }
    *(float2*)(att_res + (size_t)b * R_ + rr) = make_float2(acx, acy);
}

// ---------------- kernel 5: sums GEMM (MFMA, 3 phases, split-K=2) --------------
__global__ __launch_bounds__(256)
void sums_gemm_mfma(const float* __restrict__ x,
                    const float* __restrict__ prev_h,
                    const float* __restrict__ att_res,
                    const float* __restrict__ i2h_w,
                    const float* __restrict__ h2h_w,
                    const float* __restrict__ r2a_w,
                    float* __restrict__ P0,
                    float* __restrict__ P1) {
    __shared__ alignas(16) __bf16 As[64][40];
    __shared__ alignas(16) __bf16 Bs[64][40];
    int tid = threadIdx.x;
    int m0 = blockIdx.x * 64, n0 = blockIdx.y * 64;
    int ks = blockIdx.z;
    int kbeg = ks * 512, kend = kbeg + 512;
    int lane = tid & 63, w = tid >> 6, ln = lane & 15, quad = lane >> 4;
    int arow = tid >> 2, akq = (tid & 3) * 8;

    f32x4 acc[4];
#pragma unroll
    for (int t = 0; t < 4; ++t) acc[t] = {0.f, 0.f, 0.f, 0.f};

    const float* Al[3] = {x, prev_h, att_res};
    const float* Bl[3] = {i2h_w, h2h_w, r2a_w};
    for (int p = 0; p < 3; ++p) {
        const float* Asrc = Al[p] + (size_t)(m0 + arow) * R_ + akq;
        const float* Bsrc = Bl[p] + (size_t)(n0 + arow) * R_ + akq;
        float4 pa0 = *(const float4*)(Asrc + kbeg);
        float4 pa1 = *(const float4*)(Asrc + kbeg + 4);
        float4 pb0 = *(const float4*)(Bsrc + kbeg);
        float4 pb1 = *(const float4*)(Bsrc + kbeg + 4);
        for (int k0 = kbeg; k0 < kend; k0 += 32) {
            __syncthreads();
            *(bf16x8*)&As[arow][akq] = cvt8(pa0, pa1);
            *(bf16x8*)&Bs[arow][akq] = cvt8(pb0, pb1);
            __syncthreads();
            if (k0 + 32 < kend) {
                pa0 = *(const float4*)(Asrc + k0 + 32);
                pa1 = *(const float4*)(Asrc + k0 + 36);
                pb0 = *(const float4*)(Bsrc + k0 + 32);
                pb1 = *(const float4*)(Bsrc + k0 + 36);
            }
            bf16x8 a = *(bf16x8*)&As[w * 16 + ln][quad * 8];
#pragma unroll
            for (int t = 0; t < 4; ++t) {
                bf16x8 b = *(bf16x8*)&Bs[t * 16 + ln][quad * 8];
                acc[t] = __builtin_amdgcn_mfma_f32_16x16x32_bf16(a, b, acc[t], 0, 0, 0);
            }
        }
    }
    float* P = ks ? P1 : P0;
#pragma unroll
    for (int t = 0; t < 4; ++t) {
#pragma unroll
        for (int r = 0; r < 4; ++r) {
            int m = m0 + w * 16 + quad * 4 + r;
            int n = n0 + t * 16 + ln;
            P[(size_t)m * G4 + n] = acc[t][r];
        }
    }
}

// ---------------- kernel 6: LSTM gates ----------------------------------------
__global__ void gates_kernel(const float* __restrict__ P0,
                             const float* __restrict__ P1,
                             const float* __restrict__ i2h_b,
                             const float* __restrict__ h2h_b,
                             const float* __restrict__ r2a_b,
                             const float* __restrict__ prev_c,
                             float* __restrict__ out_c,
                             float* __restrict__ out_h,
                             __bf16* __restrict__ nh_bf) {
    int idx = blockIdx.x * 256 + threadIdx.x;
    int b = idx >> 10, r = idx & 1023;
    size_t off = (size_t)b * G4;
    float s0 = P0[off + r] + P1[off + r] + i2h_b[r] + h2h_b[r] + r2a_b[r];
    float s1 = P0[off + R_ + r] + P1[off + R_ + r] + i2h_b[R_ + r] + h2h_b[R_ + r] + r2a_b[R_ + r];
    float s2 = P0[off + 2 * R_ + r] + P1[off + 2 * R_ + r] + i2h_b[2 * R_ + r] + h2h_b[2 * R_ + r] + r2a_b[2 * R_ + r];
    float s3 = P0[off + 3 * R_ + r] + P1[off + 3 * R_ + r] + i2h_b[3 * R_ + r] + h2h_b[3 * R_ + r] + r2a_b[3 * R_ + r];
    float ig = sigmoid_fast(s0);
    float fg = sigmoid_fast(s1);
    float og = sigmoid_fast(s2);
    float it = tanh_fast(s3);
    float nc = fg * prev_c[idx] + ig * it;
    float nh = og * tanh_fast(nc);
    out_c[idx] = nc;
    out_h[idx] = nh;
    nh_bf[idx] = (__bf16)nh;
}

// ---------------- kernel 7: proj GEMM (MFMA) -----------------------------------
__global__ __launch_bounds__(256)
void proj_gemm_mfma(const __bf16* __restrict__ nh_bf,
                    const float* __restrict__ proj_w,
                    const float* __restrict__ proj_b,
                    float* __restrict__ logits) {
    __shared__ alignas(16) __bf16 As[64][40];
    __shared__ alignas(16) __bf16 Bs[64][40];
    int tid = threadIdx.x;
    int m0 = blockIdx.x * 64, n0 = blockIdx.y * 64;
    int lane = tid & 63, w = tid >> 6, ln = lane & 15, quad = lane >> 4;
    int arow = tid >> 2, akq = (tid & 3) * 8;

    f32x4 acc[4];
#pragma unroll
    for (int t = 0; t < 4; ++t) acc[t] = {0.f, 0.f, 0.f, 0.f};

    int nr = n0 + arow;
    int nrc = nr < V_ ? nr : V_ - 1;
    const __bf16* Asrc = nh_bf + (size_t)(m0 + arow) * R_ + akq;
    const float* Bsrc = proj_w + (size_t)nrc * R_ + akq;

    bf16x8 pa = *(const bf16x8*)Asrc;
    float4 pb0 = *(const float4*)Bsrc;
    float4 pb1 = *(const float4*)(Bsrc + 4);

    for (int k0 = 0; k0 < R_; k0 += 32) {
        __syncthreads();
        *(bf16x8*)&As[arow][akq] = pa;
        *(bf16x8*)&Bs[arow][akq] = cvt8(pb0, pb1);
        __syncthreads();
        if (k0 + 32 < R_) {
            pa = *(const bf16x8*)(Asrc + k0 + 32);
            pb0 = *(const float4*)(Bsrc + k0 + 32);
            pb1 = *(const float4*)(Bsrc + k0 + 36);
        }
        bf16x8 a = *(bf16x8*)&As[w * 16 + ln][quad * 8];
#pragma unroll
        for (int t = 0; t < 4; ++t) {
            bf16x8 b = *(bf16x8*)&Bs[t * 16 + ln][quad * 8];
            acc[t] = __builtin_amdgcn_mfma_f32_16x16x32_bf16(a, b, acc[t], 0, 0, 0);
        }
    }
#pragma unroll
    for (int t = 0; t < 4; ++t) {
#pragma unroll
        for (int r = 0; r < 4; ++r) {
            int m = m0 + w * 16 + quad * 4 + r;
            int n = n0 + t * 16 + ln;
            if (n < V_) logits[(size_t)m * V_ + n] = acc[t][r] + proj_b[n];
        }
    }
}

// ---------------- kernel 8: log_softmax over V per row -------------------------
__global__ void logsoftmax_kernel(const float* __restrict__ logits,
                                  float* __restrict__ out) {
    int b = blockIdx.x, t = threadIdx.x;
    __shared__ float red[256];
    const float* lp = logits + (size_t)b * V_;
    float mx = -1e30f;
    for (int v = t; v < V_; v += 256) mx = fmaxf(mx, lp[v]);
    red[t] = mx; __syncthreads();
    for (int off = 128; off > 0; off >>= 1) {
        if (t < off) red[t] = fmaxf(red[t], red[t + off]);
        __syncthreads();
    }
    mx = red[0]; __syncthreads();
    float s = 0.f;
    for (int v = t; v < V_; v += 256) s += __expf(lp[v] - mx);
    red[t] = s; __syncthreads();
    for (int off = 128; off > 0; off >>= 1) {
        if (t < off) red[t] += red[t + off];
        __syncthreads();
    }
    float lse = mx + __logf(red[0]);
    float* op = out + (size_t)b * V_;
    for (int v = t; v < V_; v += 256) op[v] = lp[v] - lse;
}

extern "C" void kernel_launch(void* const* d_in, const int* in_sizes, int n_in,
                              void* d_out, int out_size, void* d_ws, size_t ws_size,
                              hipStream_t stream) {
    const float* x      = (const float*)d_in[0];
    const float* att    = (const float*)d_in[1];
    const float* prev_c = (const float*)d_in[2];
    const float* prev_h = (const float*)d_in[3];
    const float* a2a_w  = (const float*)d_in[4];
    const float* a2a_b  = (const float*)d_in[5];
    const float* h2a_w  = (const float*)d_in[6];
    const float* h2a_b  = (const float*)d_in[7];
    const float* d2d_w  = (const float*)d_in[8];
    const float* d2d_b  = (const float*)d_in[9];
    const float* i2h_w  = (const float*)d_in[10];
    const float* i2h_b  = (const float*)d_in[11];
    const float* h2h_w  = (const float*)d_in[12];
    const float* h2h_b  = (const float*)d_in[13];
    const float* r2a_w  = (const float*)d_in[14];
    const float* r2a_b  = (const float*)d_in[15];
    const float* proj_w = (const float*)d_in[16];
    const float* proj_b = (const float*)d_in[17];

    float* ws      = (float*)d_ws;
    float* att_h   = ws + OFF_ATTH;
    float* att_res = ws + OFF_ATTRES;
    float* P0      = ws + OFF_P0;
    float* P1      = ws + OFF_P1;
    __bf16* nh_bf  = (__bf16*)(ws + OFF_NHBF);
    float* logits  = ws + OFF_LOGITS;
    __bf16* packA  = (__bf16*)(ws + OFF_PACKA);
    __bf16* packH  = (__bf16*)(ws + OFF_PACKH);
    float* out     = (float*)d_out;

    pack_kernel<<<464, 256, 0, stream>>>(a2a_w, h2a_w, packA, packH);
    att_h_gemm<<<dim3(B_ / 64, 4), 256, 0, stream>>>(prev_h, packH, h2a_b, att_h);
    att_fused<<<B_, 512, 0, stream>>>(att, packA, a2a_b, d2d_w, d2d_b, att_h, att_res);
    sums_gemm_mfma<<<dim3(B_ / 64, G4 / 64, 2), 256, 0, stream>>>(
        x, prev_h, att_res, i2h_w, h2h_w, r2a_w, P0, P1);
    gates_kernel<<<(B_ * R_) / 256, 256, 0, stream>>>(
        P0, P1, i2h_b, h2h_b, r2a_b, prev_c, out, out + B_ * R_, nh_bf);
    proj_gemm_mfma<<<dim3(B_ / 64, (V_ + 63) / 64), 256, 0, stream>>>(
        nh_bf, proj_w, proj_b, logits);
    logsoftmax_kernel<<<B_, 256, 0, stream>>>(logits, out + 2 * B_ * R_);
}

// Round 6
// 571.698 us; speedup vs baseline: 1.0072x; 1.0072x over previous
//
#include <hip/hip_runtime.h>
#include <math.h>

#define B_ 256
#define A_ 196
#define R_ 1024
#define V_ 10000
#define G4 4096
#define M_ (B_ * A_)   // 50176

typedef __bf16 bf16x8 __attribute__((ext_vector_type(8)));
typedef float f32x4 __attribute__((ext_vector_type(4)));

// ws layout in floats (~21.8 MB)
#define OFF_ATTH   0
#define OFF_SCORE  50176
#define OFF_WEIGHT 100352
#define OFF_ATTRES 150528
#define OFF_P0     412672
#define OFF_P1     1461248
#define OFF_NHBF   2509824
#define OFF_LOGITS 2640896
#define OFF_PACKA  5200896   // a2a_w bf16 [208][1024]
#define OFF_PACKH  5307392   // h2a_w bf16 [256][1024]

__device__ __forceinline__ float tanh_fast(float x) {
    float e = __expf(2.f * x);
    return 1.f - 2.f / (e + 1.f);
}
__device__ __forceinline__ float sigmoid_fast(float x) {
    return 1.f / (1.f + __expf(-x));
}

__device__ __forceinline__ bf16x8 cvt8(float4 f0, float4 f1) {
    bf16x8 v;
    v[0] = (__bf16)f0.x; v[1] = (__bf16)f0.y; v[2] = (__bf16)f0.z; v[3] = (__bf16)f0.w;
    v[4] = (__bf16)f1.x; v[5] = (__bf16)f1.y; v[6] = (__bf16)f1.z; v[7] = (__bf16)f1.w;
    return v;
}

// ---------------- kernel 0: pack a2a_w and h2a_w to bf16 (zero-padded rows) ---
__global__ void pack_kernel(const float* __restrict__ a2a_w,
                            const float* __restrict__ h2a_w,
                            __bf16* __restrict__ packA,   // [208][1024]
                            __bf16* __restrict__ packH) { // [256][1024]
    int row = blockIdx.x;
    int c = threadIdx.x * 4;
    if (row < 208) {
        float4 f = (row < A_) ? *(const float4*)(a2a_w + (size_t)row * R_ + c)
                              : make_float4(0.f, 0.f, 0.f, 0.f);
        __bf16* p = packA + (size_t)row * R_ + c;
        p[0] = (__bf16)f.x; p[1] = (__bf16)f.y; p[2] = (__bf16)f.z; p[3] = (__bf16)f.w;
    } else {
        int r2 = row - 208;
        float4 f = (r2 < A_) ? *(const float4*)(h2a_w + (size_t)r2 * R_ + c)
                             : make_float4(0.f, 0.f, 0.f, 0.f);
        __bf16* p = packH + (size_t)r2 * R_ + c;
        p[0] = (__bf16)f.x; p[1] = (__bf16)f.y; p[2] = (__bf16)f.z; p[3] = (__bf16)f.w;
    }
}

// ---------------- kernel 1: att_h = prev_h @ h2a_w.T + h2a_b  (MFMA) ----------
__global__ __launch_bounds__(256)
void att_h_gemm(const float* __restrict__ prev_h,
                const __bf16* __restrict__ packH,
                const float* __restrict__ h2a_b,
                float* __restrict__ att_h) {
    __shared__ alignas(16) __bf16 As[64][40];
    __shared__ alignas(16) __bf16 Bs[64][40];
    int tid = threadIdx.x;
    int m0 = blockIdx.x * 64, n0 = blockIdx.y * 64;
    int lane = tid & 63, w = tid >> 6, ln = lane & 15, quad = lane >> 4;
    int arow = tid >> 2, akq = (tid & 3) * 8;

    f32x4 acc[4];
#pragma unroll
    for (int t = 0; t < 4; ++t) acc[t] = {0.f, 0.f, 0.f, 0.f};

    const float* Asrc = prev_h + (size_t)(m0 + arow) * R_ + akq;
    const __bf16* Bsrc = packH + (size_t)(n0 + arow) * R_ + akq;

    float4 pa0 = *(const float4*)Asrc;
    float4 pa1 = *(const float4*)(Asrc + 4);
    bf16x8 pb = *(const bf16x8*)Bsrc;

    for (int k0 = 0; k0 < R_; k0 += 32) {
        __syncthreads();
        *(bf16x8*)&As[arow][akq] = cvt8(pa0, pa1);
        *(bf16x8*)&Bs[arow][akq] = pb;
        __syncthreads();
        if (k0 + 32 < R_) {
            pa0 = *(const float4*)(Asrc + k0 + 32);
            pa1 = *(const float4*)(Asrc + k0 + 36);
            pb = *(const bf16x8*)(Bsrc + k0 + 32);
        }
        bf16x8 a = *(bf16x8*)&As[w * 16 + ln][quad * 8];
#pragma unroll
        for (int t = 0; t < 4; ++t) {
            bf16x8 b = *(bf16x8*)&Bs[t * 16 + ln][quad * 8];
            acc[t] = __builtin_amdgcn_mfma_f32_16x16x32_bf16(a, b, acc[t], 0, 0, 0);
        }
    }
#pragma unroll
    for (int t = 0; t < 4; ++t) {
#pragma unroll
        for (int r = 0; r < 4; ++r) {
            int m = m0 + w * 16 + quad * 4 + r;
            int n = n0 + t * 16 + ln;
            if (n < A_) att_h[m * A_ + n] = acc[t][r] + h2a_b[n];
        }
    }
}

// ---------------- kernel 2: FUSED score GEMM + softmax + att_res ---------------
// One block per batch (256 blocks = 1/CU), 512 threads = 8 independent waves,
// no barriers in the GEMM loop. B (packA, L2-hot) and A (att, HBM) both go
// direct-to-register, but ISSUE ORDER is pinned per phase:
//     [all 13 B(p) loads] | fence | [4 A(p+1) loads] | fence | MFMAs
// vmcnt is FIFO, so the compiler's wait for B(p) before the MFMAs is
// vmcnt(4) -- the A(p+1) prefetch stays in flight across the whole MFMA
// block and the next phase's B issue (fix for round-4's vmcnt(0) drain that
// serialized every phase on loaded HBM latency).
// Then in-block softmax, then att_res with 2-group i-split + float4 + 7-unroll.
__global__ __launch_bounds__(512, 1)
void att_fused(const float* __restrict__ att,
               const __bf16* __restrict__ packA,  // [208][1024] bf16, zero-padded
               const float* __restrict__ a2a_b,
               const float* __restrict__ d2d_w,
               const float* __restrict__ d2d_b,
               const float* __restrict__ att_h,   // [B][196]
               float* __restrict__ att_res) {
    __shared__ float sm[256];    // scores then weights
    __shared__ float red[512];
    __shared__ float4 part[256];
    const int b = blockIdx.x;
    const int tid = threadIdx.x;
    const int w = tid >> 6, lane = tid & 63, ln = lane & 15, quad = lane >> 4;

    // A row slots for this wave's two 16-row fragments
    int r0 = w * 32 + ln;        int r0c = r0 < A_ ? r0 : A_ - 1;
    int r1 = w * 32 + 16 + ln;   int r1c = r1 < A_ ? r1 : A_ - 1;
    const float* Ap0 = att + (size_t)(b * A_ + r0c) * R_ + quad * 8;
    const float* Ap1 = att + (size_t)(b * A_ + r1c) * R_ + quad * 8;
    const __bf16* Bb = packA + (size_t)ln * R_ + quad * 8;

    f32x4 acc0[13], acc1[13];
#pragma unroll
    for (int t = 0; t < 13; ++t) {
        acc0[t] = {0.f, 0.f, 0.f, 0.f};
        acc1[t] = {0.f, 0.f, 0.f, 0.f};
    }

    // A phase-0 in flight
    float4 a00 = *(const float4*)Ap0, a01 = *(const float4*)(Ap0 + 4);
    float4 a10 = *(const float4*)Ap1, a11 = *(const float4*)(Ap1 + 4);

    for (int p = 0; p < 32; ++p) {
        // B(p): ALL 13 fragments issued first (oldest in FIFO)
        bf16x8 bt[13];
#pragma unroll
        for (int t = 0; t < 13; ++t)
            bt[t] = *(const bf16x8*)(Bb + (size_t)t * 16 * R_ + p * 32);
        asm volatile("" ::: "memory");   // fence: keep A-issue after all B-issue
        // A(p+1) prefetch: youngest in FIFO -> any B-wait leaves these in flight
        int pn = p + 1 < 32 ? p + 1 : 31;
        float4 n00 = *(const float4*)(Ap0 + pn * 32);
        float4 n01 = *(const float4*)(Ap0 + pn * 32 + 4);
        float4 n10 = *(const float4*)(Ap1 + pn * 32);
        float4 n11 = *(const float4*)(Ap1 + pn * 32 + 4);
        asm volatile("" ::: "memory");   // fence: MFMAs/waits after both streams
        bf16x8 af0 = cvt8(a00, a01);
        bf16x8 af1 = cvt8(a10, a11);
#pragma unroll
        for (int t = 0; t < 13; ++t) {
            acc0[t] = __builtin_amdgcn_mfma_f32_16x16x32_bf16(af0, bt[t], acc0[t], 0, 0, 0);
            acc1[t] = __builtin_amdgcn_mfma_f32_16x16x32_bf16(af1, bt[t], acc1[t], 0, 0, 0);
        }
        a00 = n00; a01 = n01; a10 = n10; a11 = n11;
    }

    // ---- epilogue: tanh + d2d dot, wave-local shuffle reduce over ln ----
    float wv[13], bb2[13];
#pragma unroll
    for (int t = 0; t < 13; ++t) {
        int n = t * 16 + ln;
        wv[t] = (n < A_) ? d2d_w[n] : 0.f;
        bb2[t] = (n < A_) ? a2a_b[n] : 0.f;
    }
#pragma unroll
    for (int mf = 0; mf < 2; ++mf) {
#pragma unroll
        for (int r = 0; r < 4; ++r) {
            int slot = w * 32 + mf * 16 + quad * 4 + r;
            float ah = (slot < A_) ? att_h[b * A_ + slot] : 0.f;
            float pv = 0.f;
#pragma unroll
            for (int t = 0; t < 13; ++t) {
                float v = (mf == 0) ? acc0[t][r] : acc1[t][r];
                pv += tanh_fast(v + bb2[t] + ah) * wv[t];
            }
            pv += __shfl_xor(pv, 1);
            pv += __shfl_xor(pv, 2);
            pv += __shfl_xor(pv, 4);
            pv += __shfl_xor(pv, 8);
            if (ln == 0 && slot < A_) sm[slot] = pv;
        }
    }
    __syncthreads();

    // ---- softmax over 196 scores (512-thread tree) ----
    float sval = 0.f, s = -1e30f;
    if (tid < A_) { sval = sm[tid] + d2d_b[0]; s = sval; }
    red[tid] = s; __syncthreads();
    for (int off = 256; off > 0; off >>= 1) {
        if (tid < off) red[tid] = fmaxf(red[tid], red[tid + off]);
        __syncthreads();
    }
    float mx = red[0]; __syncthreads();
    float e = (tid < A_) ? __expf(sval - mx) : 0.f;
    red[tid] = e; __syncthreads();
    for (int off = 256; off > 0; off >>= 1) {
        if (tid < off) red[tid] += red[tid + off];
        __syncthreads();
    }
    float inv = 1.f / red[0];
    if (tid < A_) sm[tid] = e * inv;
    __syncthreads();

    // ---- att_res: 2 thread-groups split the i-sum; float4 cols; 7-row unroll --
    {
        int g = tid >> 8;                 // 0 or 1
        int col = (tid & 255) * 4;
        int ibeg = g * 98;                // 98 + 98 = 196
        const float* ap = att + (size_t)b * A_ * R_ + col;
        float4 acc = make_float4(0.f, 0.f, 0.f, 0.f);
        for (int i = ibeg; i < ibeg + 98; i += 7) {
            float4 v0 = *(const float4*)(ap + (size_t)(i + 0) * R_);
            float4 v1 = *(const float4*)(ap + (size_t)(i + 1) * R_);
            float4 v2 = *(const float4*)(ap + (size_t)(i + 2) * R_);
            float4 v3 = *(const float4*)(ap + (size_t)(i + 3) * R_);
            float4 v4 = *(const float4*)(ap + (size_t)(i + 4) * R_);
            float4 v5 = *(const float4*)(ap + (size_t)(i + 5) * R_);
            float4 v6 = *(const float4*)(ap + (size_t)(i + 6) * R_);
            float w0 = sm[i], w1 = sm[i + 1], w2 = sm[i + 2], w3 = sm[i + 3];
            float w4 = sm[i + 4], w5 = sm[i + 5], w6 = sm[i + 6];
            acc.x += v0.x * w0 + v1.x * w1 + v2.x * w2 + v3.x * w3 + v4.x * w4 + v5.x * w5 + v6.x * w6;
            acc.y += v0.y * w0 + v1.y * w1 + v2.y * w2 + v3.y * w3 + v4.y * w4 + v5.y * w5 + v6.y * w6;
            acc.z += v0.z * w0 + v1.z * w1 + v2.z * w2 + v3.z * w3 + v4.z * w4 + v5.z * w5 + v6.z * w6;
            acc.w += v0.w * w0 + v1.w * w1 + v2.w * w2 + v3.w * w3 + v4.w * w4 + v5.w * w5 + v6.w * w6;
        }
        if (g == 1) part[tid & 255] = acc;
        __syncthreads();
        if (g == 0) {
            float4 p2 = part[tid];
            acc.x += p2.x; acc.y += p2.y; acc.z += p2.z; acc.w += p2.w;
            *(float4*)(att_res + (size_t)b * R_ + col) = acc;
        }
    }
}

// ---------------- kernel 5: sums GEMM (MFMA, 3 phases, split-K=2) --------------
__global__ __launch_bounds__(256)
void sums_gemm_mfma(const float* __restrict__ x,
                    const float* __restrict__ prev_h,
                    const float* __restrict__ att_res,
                    const float* __restrict__ i2h_w,
                    const float* __restrict__ h2h_w,
                    const float* __restrict__ r2a_w,
                    float* __restrict__ P0,
                    float* __restrict__ P1) {
    __shared__ alignas(16) __bf16 As[64][40];
    __shared__ alignas(16) __bf16 Bs[64][40];
    int tid = threadIdx.x;
    int m0 = blockIdx.x * 64, n0 = blockIdx.y * 64;
    int ks = blockIdx.z;
    int kbeg = ks * 512, kend = kbeg + 512;
    int lane = tid & 63, w = tid >> 6, ln = lane & 15, quad = lane >> 4;
    int arow = tid >> 2, akq = (tid & 3) * 8;

    f32x4 acc[4];
#pragma unroll
    for (int t = 0; t < 4; ++t) acc[t] = {0.f, 0.f, 0.f, 0.f};

    const float* Al[3] = {x, prev_h, att_res};
    const float* Bl[3] = {i2h_w, h2h_w, r2a_w};
    for (int p = 0; p < 3; ++p) {
        const float* Asrc = Al[p] + (size_t)(m0 + arow) * R_ + akq;
        const float* Bsrc = Bl[p] + (size_t)(n0 + arow) * R_ + akq;
        float4 pa0 = *(const float4*)(Asrc + kbeg);
        float4 pa1 = *(const float4*)(Asrc + kbeg + 4);
        float4 pb0 = *(const float4*)(Bsrc + kbeg);
        float4 pb1 = *(const float4*)(Bsrc + kbeg + 4);
        for (int k0 = kbeg; k0 < kend; k0 += 32) {
            __syncthreads();
            *(bf16x8*)&As[arow][akq] = cvt8(pa0, pa1);
            *(bf16x8*)&Bs[arow][akq] = cvt8(pb0, pb1);
            __syncthreads();
            if (k0 + 32 < kend) {
                pa0 = *(const float4*)(Asrc + k0 + 32);
                pa1 = *(const float4*)(Asrc + k0 + 36);
                pb0 = *(const float4*)(Bsrc + k0 + 32);
                pb1 = *(const float4*)(Bsrc + k0 + 36);
            }
            bf16x8 a = *(bf16x8*)&As[w * 16 + ln][quad * 8];
#pragma unroll
            for (int t = 0; t < 4; ++t) {
                bf16x8 b = *(bf16x8*)&Bs[t * 16 + ln][quad * 8];
                acc[t] = __builtin_amdgcn_mfma_f32_16x16x32_bf16(a, b, acc[t], 0, 0, 0);
            }
        }
    }
    float* P = ks ? P1 : P0;
#pragma unroll
    for (int t = 0; t < 4; ++t) {
#pragma unroll
        for (int r = 0; r < 4; ++r) {
            int m = m0 + w * 16 + quad * 4 + r;
            int n = n0 + t * 16 + ln;
            P[(size_t)m * G4 + n] = acc[t][r];
        }
    }
}

// ---------------- kernel 6: LSTM gates ----------------------------------------
__global__ void gates_kernel(const float* __restrict__ P0,
                             const float* __restrict__ P1,
                             const float* __restrict__ i2h_b,
                             const float* __restrict__ h2h_b,
                             const float* __restrict__ r2a_b,
                             const float* __restrict__ prev_c,
                             float* __restrict__ out_c,
                             float* __restrict__ out_h,
                             __bf16* __restrict__ nh_bf) {
    int idx = blockIdx.x * 256 + threadIdx.x;
    int b = idx >> 10, r = idx & 1023;
    size_t off = (size_t)b * G4;
    float s0 = P0[off + r] + P1[off + r] + i2h_b[r] + h2h_b[r] + r2a_b[r];
    float s1 = P0[off + R_ + r] + P1[off + R_ + r] + i2h_b[R_ + r] + h2h_b[R_ + r] + r2a_b[R_ + r];
    float s2 = P0[off + 2 * R_ + r] + P1[off + 2 * R_ + r] + i2h_b[2 * R_ + r] + h2h_b[2 * R_ + r] + r2a_b[2 * R_ + r];
    float s3 = P0[off + 3 * R_ + r] + P1[off + 3 * R_ + r] + i2h_b[3 * R_ + r] + h2h_b[3 * R_ + r] + r2a_b[3 * R_ + r];
    float ig = sigmoid_fast(s0);
    float fg = sigmoid_fast(s1);
    float og = sigmoid_fast(s2);
    float it = tanh_fast(s3);
    float nc = fg * prev_c[idx] + ig * it;
    float nh = og * tanh_fast(nc);
    out_c[idx] = nc;
    out_h[idx] = nh;
    nh_bf[idx] = (__bf16)nh;
}

// ---------------- kernel 7: proj GEMM (MFMA) -----------------------------------
__global__ __launch_bounds__(256)
void proj_gemm_mfma(const __bf16* __restrict__ nh_bf,
                    const float* __restrict__ proj_w,
                    const float* __restrict__ proj_b,
                    float* __restrict__ logits) {
    __shared__ alignas(16) __bf16 As[64][40];
    __shared__ alignas(16) __bf16 Bs[64][40];
    int tid = threadIdx.x;
    int m0 = blockIdx.x * 64, n0 = blockIdx.y * 64;
    int lane = tid & 63, w = tid >> 6, ln = lane & 15, quad = lane >> 4;
    int arow = tid >> 2, akq = (tid & 3) * 8;

    f32x4 acc[4];
#pragma unroll
    for (int t = 0; t < 4; ++t) acc[t] = {0.f, 0.f, 0.f, 0.f};

    int nr = n0 + arow;
    int nrc = nr < V_ ? nr : V_ - 1;
    const __bf16* Asrc = nh_bf + (size_t)(m0 + arow) * R_ + akq;
    const float* Bsrc = proj_w + (size_t)nrc * R_ + akq;

    bf16x8 pa = *(const bf16x8*)Asrc;
    float4 pb0 = *(const float4*)Bsrc;
    float4 pb1 = *(const float4*)(Bsrc + 4);

    for (int k0 = 0; k0 < R_; k0 += 32) {
        __syncthreads();
        *(bf16x8*)&As[arow][akq] = pa;
        *(bf16x8*)&Bs[arow][akq] = cvt8(pb0, pb1);
        __syncthreads();
        if (k0 + 32 < R_) {
            pa = *(const bf16x8*)(Asrc + k0 + 32);
            pb0 = *(const float4*)(Bsrc + k0 + 32);
            pb1 = *(const float4*)(Bsrc + k0 + 36);
        }
        bf16x8 a = *(bf16x8*)&As[w * 16 + ln][quad * 8];
#pragma unroll
        for (int t = 0; t < 4; ++t) {
            bf16x8 b = *(bf16x8*)&Bs[t * 16 + ln][quad * 8];
            acc[t] = __builtin_amdgcn_mfma_f32_16x16x32_bf16(a, b, acc[t], 0, 0, 0);
        }
    }
#pragma unroll
    for (int t = 0; t < 4; ++t) {
#pragma unroll
        for (int r = 0; r < 4; ++r) {
            int m = m0 + w * 16 + quad * 4 + r;
            int n = n0 + t * 16 + ln;
            if (n < V_) logits[(size_t)m * V_ + n] = acc[t][r] + proj_b[n];
        }
    }
}

// ---------------- kernel 8: log_softmax over V per row -------------------------
__global__ void logsoftmax_kernel(const float* __restrict__ logits,
                                  float* __restrict__ out) {
    int b = blockIdx.x, t = threadIdx.x;
    __shared__ float red[256];
    const float* lp = logits + (size_t)b * V_;
    float mx = -1e30f;
    for (int v = t; v < V_; v += 256) mx = fmaxf(mx, lp[v]);
    red[t] = mx; __syncthreads();
    for (int off = 128; off > 0; off >>= 1) {
        if (t < off) red[t] = fmaxf(red[t], red[t + off]);
        __syncthreads();
    }
    mx = red[0]; __syncthreads();
    float s = 0.f;
    for (int v = t; v < V_; v += 256) s += __expf(lp[v] - mx);
    red[t] = s; __syncthreads();
    for (int off = 128; off > 0; off >>= 1) {
        if (t < off) red[t] += red[t + off];
        __syncthreads();
    }
    float lse = mx + __logf(red[0]);
    float* op = out + (size_t)b * V_;
    for (int v = t; v < V_; v += 256) op[v] = lp[v] - lse;
}

extern "C" void kernel_launch(void* const* d_in, const int* in_sizes, int n_in,
                              void* d_out, int out_size, void* d_ws, size_t ws_size,
                              hipStream_t stream) {
    const float* x      = (const float*)d_in[0];
    const float* att    = (const float*)d_in[1];
    const float* prev_c = (const float*)d_in[2];
    const float* prev_h = (const float*)d_in[3];
    const float* a2a_w  = (const float*)d_in[4];
    const float* a2a_b  = (const float*)d_in[5];
    const float* h2a_w  = (const float*)d_in[6];
    const float* h2a_b  = (const float*)d_in[7];
    const float* d2d_w  = (const float*)d_in[8];
    const float* d2d_b  = (const float*)d_in[9];
    const float* i2h_w  = (const float*)d_in[10];
    const float* i2h_b  = (const float*)d_in[11];
    const float* h2h_w  = (const float*)d_in[12];
    const float* h2h_b  = (const float*)d_in[13];
    const float* r2a_w  = (const float*)d_in[14];
    const float* r2a_b  = (const float*)d_in[15];
    const float* proj_w = (const float*)d_in[16];
    const float* proj_b = (const float*)d_in[17];

    float* ws      = (float*)d_ws;
    float* att_h   = ws + OFF_ATTH;
    float* att_res = ws + OFF_ATTRES;
    float* P0      = ws + OFF_P0;
    float* P1      = ws + OFF_P1;
    __bf16* nh_bf  = (__bf16*)(ws + OFF_NHBF);
    float* logits  = ws + OFF_LOGITS;
    __bf16* packA  = (__bf16*)(ws + OFF_PACKA);
    __bf16* packH  = (__bf16*)(ws + OFF_PACKH);
    float* out     = (float*)d_out;

    pack_kernel<<<464, 256, 0, stream>>>(a2a_w, h2a_w, packA, packH);
    att_h_gemm<<<dim3(B_ / 64, 4), 256, 0, stream>>>(prev_h, packH, h2a_b, att_h);
    att_fused<<<B_, 512, 0, stream>>>(att, packA, a2a_b, d2d_w, d2d_b, att_h, att_res);
    sums_gemm_mfma<<<dim3(B_ / 64, G4 / 64, 2), 256, 0, stream>>>(
        x, prev_h, att_res, i2h_w, h2h_w, r2a_w, P0, P1);
    gates_kernel<<<(B_ * R_) / 256, 256, 0, stream>>>(
        P0, P1, i2h_b, h2h_b, r2a_b, prev_c, out, out + B_ * R_, nh_bf);
    proj_gemm_mfma<<<dim3(B_ / 64, (V_ + 63) / 64), 256, 0, stream>>>(
        nh_bf, proj_w, proj_b, logits);
    logsoftmax_kernel<<<B_, 256, 0, stream>>>(logits, out + 2 * B_ * R_);
}